// Round 15
// baseline (202.118 us; speedup 1.0000x reference)
//
#include <hip/hip_runtime.h>
#include <hip/hip_bf16.h>

#define DHID 64
#define SUBSH 9
#define SUBSZ (1 << SUBSH)     // 512 dst nodes per sub-bucket
#define PCAP 16384             // LDS staging cap (ints) in k_place2
#define EB 2048                // edges per block in bucket pass
typedef __attribute__((ext_vector_type(8))) short short8;
typedef __attribute__((ext_vector_type(4))) float f32x4;

static __device__ __forceinline__ short tobf(float f) {
  __hip_bfloat16 h = __float2bfloat16(f);
  return *reinterpret_cast<short*>(&h);
}

// ---------- fused A: edge bucket partition (blocks < nbkt) || layer-1 MFMA gemm ----------
__global__ __launch_bounds__(256)
void k_fusedA(const int* __restrict__ src, const int* __restrict__ dst,
              int* __restrict__ bkt, int* __restrict__ bcnt,
              int E, int nsb, int cap, int nbkt,
              const float* __restrict__ xf, const float* __restrict__ W1,
              const float* __restrict__ a_s, const float* __restrict__ a_d,
              short* __restrict__ hb, float* __restrict__ asb,
              float* __restrict__ adb, int N) {
  __shared__ int lcnt[256];
  __shared__ int lbase[256];
  __shared__ __align__(16) short ldsB[64 * 128];
  int tid = threadIdx.x;
  if (blockIdx.x < nbkt) {
    // ---- bucket path: single-pass local rank, payload (src<<9)|(d&511) ----
    int c0 = blockIdx.x * EB;
    for (int i = tid; i < nsb; i += 256) lcnt[i] = 0;
    __syncthreads();
    int wloc[8], uloc[8], rloc[8];
    #pragma unroll
    for (int k = 0; k < 8; k++) {
      int i = c0 + tid + k * 256;
      if (i < E) {
        int d = dst[i];
        int w = d >> SUBSH;
        wloc[k] = w;
        uloc[k] = (src[i] << SUBSH) | (d & (SUBSZ - 1));
        rloc[k] = atomicAdd(&lcnt[w], 1);
      } else wloc[k] = -1;
    }
    __syncthreads();
    for (int i = tid; i < nsb; i += 256) lbase[i] = atomicAdd(&bcnt[i], lcnt[i]);
    __syncthreads();
    #pragma unroll
    for (int k = 0; k < 8; k++) {
      int w = wloc[k];
      if (w >= 0) bkt[(size_t)w * cap + lbase[w] + rloc[k]] = uloc[k];
    }
    return;
  }
  // ---- mgemm1 path (K=128): A per-lane fp32->bf16; B = W1 self-converted ----
  int n0 = (blockIdx.x - nbkt) * 64;
  for (int e = tid; e < 128 * 64; e += 256) {
    int k = e >> 6, c = e & 63;
    ldsB[c * 128 + (k ^ ((c & 7) << 3))] = tobf(W1[e]);
  }
  __syncthreads();

  int l = tid & 63, w = tid >> 6;
  int c = l & 15, g = l >> 4;
  f32x4 acc[4];
  #pragma unroll
  for (int t = 0; t < 4; t++) acc[t] = (f32x4){0.f, 0.f, 0.f, 0.f};

  int arow = 16 * w + c;
  int row0 = n0 + arow;
  const float* xr = xf + (size_t)row0 * 128;
  bool okr = row0 < N;
  short8 afr[4];
  #pragma unroll
  for (int s = 0; s < 4; s++) {
    int ke = s * 32 + g * 8;
    float4 u0 = make_float4(0.f, 0.f, 0.f, 0.f), u1 = u0;
    if (okr) { u0 = *(const float4*)(xr + ke); u1 = *(const float4*)(xr + ke + 4); }
    short8 af;
    af[0] = tobf(u0.x); af[1] = tobf(u0.y); af[2] = tobf(u0.z); af[3] = tobf(u0.w);
    af[4] = tobf(u1.x); af[5] = tobf(u1.y); af[6] = tobf(u1.z); af[7] = tobf(u1.w);
    afr[s] = af;
  }
  #pragma unroll
  for (int s = 0; s < 4; s++) {
    int ke = s * 32 + g * 8;
    #pragma unroll
    for (int t = 0; t < 4; t++) {
      int bcol = 16 * t + c;
      short8 bf = *(const short8*)(ldsB + bcol * 128 + (ke ^ ((bcol & 7) << 3)));
      acc[t] = __builtin_amdgcn_mfma_f32_16x16x32_bf16(afr[s], bf, acc[t], 0, 0, 0);
    }
  }
  float av_s[4], av_d[4];
  #pragma unroll
  for (int t = 0; t < 4; t++) { av_s[t] = a_s[16 * t + c]; av_d[t] = a_d[16 * t + c]; }
  #pragma unroll
  for (int q = 0; q < 4; q++) {
    int row = n0 + 16 * w + g * 4 + q;
    bool ok = row < N;
    float rs = 0.f, rd = 0.f;
    #pragma unroll
    for (int t = 0; t < 4; t++) {
      float v = acc[t][q];
      if (ok) hb[(size_t)row * 64 + 16 * t + c] = tobf(v);
      rs += v * av_s[t]; rd += v * av_d[t];
    }
    #pragma unroll
    for (int off = 1; off < 16; off <<= 1) {
      rs += __shfl_xor(rs, off, 64);
      rd += __shfl_xor(rd, off, 64);
    }
    if (ok && c == 0) { asb[row] = rs; adb[row] = rd; }
  }
}

// ---------- merged count + scan + place (one block per sub-bucket) ----------
__global__ __launch_bounds__(256)
void k_place2(const int* __restrict__ bkt, const int* __restrict__ bcnt,
              int* __restrict__ roff, int* __restrict__ csr,
              int N, int nsb, int cap) {
  __shared__ int scanbuf[256];
  __shared__ int h[SUBSZ];
  __shared__ int roff_l[SUBSZ + 1];
  __shared__ int lcnt[SUBSZ];
  __shared__ int stage[PCAP];
  __shared__ int sbase;
  int sb = blockIdx.x, tid = threadIdx.x;
  int d0 = sb << SUBSH;
  int nn = min(N - d0, SUBSZ);

  int tot = 0;
  if (tid < nsb) tot = bcnt[tid] + min(N - (tid << SUBSH), SUBSZ);
  scanbuf[tid] = tot; __syncthreads();
  for (int off = 1; off < 256; off <<= 1) {
    int t = (tid >= off) ? scanbuf[tid - off] : 0;
    __syncthreads(); scanbuf[tid] += t; __syncthreads();
  }
  if (tid == sb) sbase = scanbuf[tid] - tot;
  __syncthreads();

  for (int j = tid; j < SUBSZ; j += 256) { h[j] = 1; lcnt[j] = 0; }
  __syncthreads();
  int nE = bcnt[sb];
  const int* b = bkt + (size_t)sb * cap;
  for (int i = tid; i < nE; i += 256) atomicAdd(&h[b[i] & (SUBSZ - 1)], 1);
  __syncthreads();

  int a0 = h[2 * tid], a1 = h[2 * tid + 1];
  int s = a0 + a1;
  scanbuf[tid] = s; __syncthreads();
  for (int off = 1; off < 256; off <<= 1) {
    int t = (tid >= off) ? scanbuf[tid - off] : 0;
    __syncthreads(); scanbuf[tid] += t; __syncthreads();
  }
  int excl = sbase + scanbuf[tid] - s;
  roff_l[2 * tid] = excl;
  roff_l[2 * tid + 1] = excl + a0;
  if (tid == 255) roff_l[SUBSZ] = sbase + scanbuf[255];
  __syncthreads();

  for (int j = tid; j < nn; j += 256) roff[d0 + j] = roff_l[j];
  if (d0 + nn == N && tid == 0) roff[N] = roff_l[nn];

  int base0 = roff_l[0];
  int span = roff_l[nn] - base0;
  if (span <= PCAP) {
    for (int d = tid; d < nn; d += 256) stage[roff_l[d] - base0] = (d0 + d) << 7; // self-loop
    for (int i = tid; i < nE; i += 256) {
      int u = b[i];
      int dl = u & (SUBSZ - 1);
      int rk = 1 + atomicAdd(&lcnt[dl], 1);
      stage[roff_l[dl] - base0 + rk] = (u >> SUBSH) << 7;
    }
    __syncthreads();
    for (int j = tid; j < span; j += 256) csr[base0 + j] = stage[j];
  } else {  // correctness fallback (never for random graphs)
    for (int d = tid; d < nn; d += 256) csr[roff_l[d]] = (d0 + d) << 7;
    for (int i = tid; i < nE; i += 256) {
      int u = b[i];
      int dl = u & (SUBSZ - 1);
      int rk = 1 + atomicAdd(&lcnt[dl], 1);
      csr[roff_l[dl] + rk] = (u >> SUBSH) << 7;
    }
  }
}

// ---------- fused agg(layer1) + MFMA gemm(layer2) ----------
// Block = 64 consecutive dst nodes. 4 waves x 16 nodes run the pipelined
// aggregation, writing emb (f32, global) and the bf16 tile into LDS (swizzled).
// One __syncthreads, then the 64x64x64 GEMM (A from LDS, B = W2 converted
// in-block). Eliminates the eb global round-trip and the separate launch.
// Layer-2 outputs go to hb2/asb2/adb2 (hb is still gather-read by other blocks).
__global__ __launch_bounds__(256)
void k_aggGemm(const int* __restrict__ roff, const int* __restrict__ csr,
               const float* __restrict__ asb, const float* __restrict__ adb,
               const short* __restrict__ hb, const float* __restrict__ b1v,
               float* __restrict__ emb,
               const float* __restrict__ W2,
               const float* __restrict__ a_s2, const float* __restrict__ a_d2,
               short* __restrict__ hb2, float* __restrict__ asb2,
               float* __restrict__ adb2, int N) {
  __shared__ __align__(16) short ldsA[64 * 64];
  __shared__ __align__(16) short ldsB[64 * 64];
  const char* hbase = (const char*)hb;
  int tid = threadIdx.x;
  int n0 = blockIdx.x * 64;
  int lane = tid & 63, w = tid >> 6;

  // B = W2 convert + swizzle (before agg phase; covered by the same barrier)
  for (int e = tid; e < 64 * 64; e += 256) {
    int k = e >> 6, c = e & 63;
    ldsB[c * 64 + (k ^ ((c & 7) << 3))] = tobf(W2[e]);
  }

  // ---- agg phase: wave w handles nodes n0+16w .. n0+16w+15, 3-stage pipeline ----
  {
    int colb = (lane & 15) * 8;
    int L = lane & 15;
    float4 bv4 = ((const float4*)b1v)[L];
    int nbase = n0 + w * 16;

    int r0c = 0, r1c = 0, sc = 0, r0n = 0, r1n = 0, sn = 0;
    float adc = 0.f, avc = 0.f, adn = 0.f;
    if (nbase < N) {
      r0c = roff[nbase]; r1c = roff[nbase + 1]; adc = adb[nbase];
      if (lane < min(64, r1c - r0c)) sc = csr[r0c + lane];
      avc = asb[sc >> 7];
    }
    if (nbase + 1 < N) {
      r0n = roff[nbase + 1]; r1n = roff[nbase + 2]; adn = adb[nbase + 1];
      if (lane < min(64, r1n - r0n)) sn = csr[r0n + lane];
    }

    for (int i = 0; i < 16; i++) {
      int n = nbase + i;
      if (n >= N) break;                 // wave-uniform
      int cnt0 = min(64, r1c - r0c);
      float e = 0.f;
      if (lane < cnt0) {
        float l = avc + adc;
        l = fmaxf(l, 0.2f * l);
        e = __expf(l);
      }
      int n2 = n + 2;
      int r02 = 0, r12 = 0; float ad2v = 0.f;
      bool p2 = (i + 2 < 16) && (n2 < N);
      if (p2) { r02 = roff[n2]; r12 = roff[n2 + 1]; ad2v = adb[n2]; }
      float avn = asb[sn >> 7];

      float a0 = 0.f, a1 = 0.f, a2 = 0.f, a3 = 0.f, denl = e;
      {
        int cntUp = (cnt0 + 3) & ~3;
        int addrv = (lane >> 4) << 2;
        #pragma unroll 4
        for (int j = 0; j < cntUp; j += 4) {
          int sofs = __builtin_amdgcn_ds_bpermute(addrv, sc);
          int ewi  = __builtin_amdgcn_ds_bpermute(addrv, (int)__float_as_uint(e));
          addrv += 16;
          float ew = __uint_as_float((unsigned)ewi);
          uint2 u = *(const uint2*)(hbase + (unsigned)(sofs + colb));
          a0 = fmaf(__uint_as_float(u.x << 16), ew, a0);
          a1 = fmaf(__uint_as_float(u.x & 0xFFFF0000u), ew, a1);
          a2 = fmaf(__uint_as_float(u.y << 16), ew, a2);
          a3 = fmaf(__uint_as_float(u.y & 0xFFFF0000u), ew, a3);
        }
      }
      for (int base = r0c + 64; base < r1c; base += 64) {   // degree>63 fallback
        int cnt = min(64, r1c - base);
        int s128 = 0; float e2 = 0.f;
        if (lane < cnt) {
          s128 = csr[base + lane];
          float l = asb[s128 >> 7] + adc;
          l = fmaxf(l, 0.2f * l);
          e2 = __expf(l);
        }
        denl += e2;
        int cntUp = (cnt + 3) & ~3;
        int addrv = (lane >> 4) << 2;
        for (int j = 0; j < cntUp; j += 4) {
          int sofs = __builtin_amdgcn_ds_bpermute(addrv, s128);
          int ewi  = __builtin_amdgcn_ds_bpermute(addrv, (int)__float_as_uint(e2));
          addrv += 16;
          float ew = __uint_as_float((unsigned)ewi);
          uint2 u = *(const uint2*)(hbase + (unsigned)(sofs + colb));
          a0 = fmaf(__uint_as_float(u.x << 16), ew, a0);
          a1 = fmaf(__uint_as_float(u.x & 0xFFFF0000u), ew, a1);
          a2 = fmaf(__uint_as_float(u.y << 16), ew, a2);
          a3 = fmaf(__uint_as_float(u.y & 0xFFFF0000u), ew, a3);
        }
      }
      #pragma unroll
      for (int off = 16; off <= 32; off <<= 1) {
        a0 += __shfl_xor(a0, off, 64); a1 += __shfl_xor(a1, off, 64);
        a2 += __shfl_xor(a2, off, 64); a3 += __shfl_xor(a3, off, 64);
      }
      float den = denl;
      #pragma unroll
      for (int off = 32; off; off >>= 1) den += __shfl_xor(den, off, 64);
      float inv = 1.f / (den + 1e-16f);
      if (lane < 16) {
        float4 o;
        o.x = fmaxf(fmaf(a0, inv, bv4.x), 0.f);
        o.y = fmaxf(fmaf(a1, inv, bv4.y), 0.f);
        o.z = fmaxf(fmaf(a2, inv, bv4.z), 0.f);
        o.w = fmaxf(fmaf(a3, inv, bv4.w), 0.f);
        ((float4*)(emb + (size_t)n * DHID))[L] = o;
        int lrow = n - n0;               // lrow&7 == n&7 (n0 multiple of 64)
        short4 ob = make_short4(tobf(o.x), tobf(o.y), tobf(o.z), tobf(o.w));
        ((short4*)(ldsA + lrow * 64))[L ^ ((lrow & 7) << 1)] = ob;
      }
      r0c = r0n; r1c = r1n; adc = adn; sc = sn; avc = avn;
      r0n = r02; r1n = r12; adn = ad2v;
      sn = 0;
      if (p2 && lane < min(64, r1n - r0n)) sn = csr[r0n + lane];
    }
  }
  __syncthreads();

  // ---- GEMM phase (64x64x64): A = ldsA, B = ldsB ----
  int c = lane & 15, g = lane >> 4;
  f32x4 acc[4];
  #pragma unroll
  for (int t = 0; t < 4; t++) acc[t] = (f32x4){0.f, 0.f, 0.f, 0.f};
  int arow = 16 * w + c;
  #pragma unroll
  for (int s = 0; s < 2; s++) {
    int ke = s * 32 + g * 8;
    short8 af = *(const short8*)(ldsA + arow * 64 + (ke ^ ((arow & 7) << 3)));
    #pragma unroll
    for (int t = 0; t < 4; t++) {
      int bcol = 16 * t + c;
      short8 bf = *(const short8*)(ldsB + bcol * 64 + (ke ^ ((bcol & 7) << 3)));
      acc[t] = __builtin_amdgcn_mfma_f32_16x16x32_bf16(af, bf, acc[t], 0, 0, 0);
    }
  }
  float av_s[4], av_d[4];
  #pragma unroll
  for (int t = 0; t < 4; t++) { av_s[t] = a_s2[16 * t + c]; av_d[t] = a_d2[16 * t + c]; }
  #pragma unroll
  for (int q = 0; q < 4; q++) {
    int row = n0 + 16 * w + g * 4 + q;
    bool ok = row < N;
    float rs = 0.f, rd = 0.f;
    #pragma unroll
    for (int t = 0; t < 4; t++) {
      float v = acc[t][q];
      if (ok) hb2[(size_t)row * 64 + 16 * t + c] = tobf(v);
      rs += v * av_s[t]; rd += v * av_d[t];
    }
    #pragma unroll
    for (int off = 1; off < 16; off <<= 1) {
      rs += __shfl_xor(rs, off, 64);
      rd += __shfl_xor(rd, off, 64);
    }
    if (ok && c == 0) { asb2[row] = rs; adb2[row] = rd; }
  }
}

// ---------- sparse: fused softmax + aggregation, 3-stage node pipeline ----------
__global__ void k_agg(const int* __restrict__ roff, const int* __restrict__ csr,
                      const float* __restrict__ asb, const float* __restrict__ adb,
                      const short* __restrict__ hb, const float* __restrict__ b,
                      float* __restrict__ out, int N) {
  const char* hbase = (const char*)hb;
  int lane = threadIdx.x & 63;
  int colb = (lane & 15) * 8;
  int L = lane & 15;
  int wid = blockIdx.x * (blockDim.x >> 6) + (threadIdx.x >> 6);
  int nw = gridDim.x * (blockDim.x >> 6);
  float4 bv4 = ((const float4*)b)[L];

  int r0c = 0, r1c = 0, sc = 0, r0n = 0, r1n = 0, sn = 0;
  float adc = 0.f, avc = 0.f, adn = 0.f;
  if (wid < N) {
    r0c = roff[wid]; r1c = roff[wid + 1]; adc = adb[wid];
    if (lane < min(64, r1c - r0c)) sc = csr[r0c + lane];
    avc = asb[sc >> 7];
  }
  if (wid + nw < N) {
    r0n = roff[wid + nw]; r1n = roff[wid + nw + 1]; adn = adb[wid + nw];
    if (lane < min(64, r1n - r0n)) sn = csr[r0n + lane];
  }

  for (int n = wid; n < N; n += nw) {
    int cnt0 = min(64, r1c - r0c);
    float e = 0.f;
    if (lane < cnt0) {
      float l = avc + adc;
      l = fmaxf(l, 0.2f * l);
      e = __expf(l);
    }
    int n2 = n + 2 * nw;
    int r02 = 0, r12 = 0; float ad2 = 0.f;
    if (n2 < N) { r02 = roff[n2]; r12 = roff[n2 + 1]; ad2 = adb[n2]; }
    float avn = asb[sn >> 7];

    float a0 = 0.f, a1 = 0.f, a2 = 0.f, a3 = 0.f, denl = e;
    {
      int cntUp = (cnt0 + 3) & ~3;
      int addrv = (lane >> 4) << 2;
      #pragma unroll 4
      for (int j = 0; j < cntUp; j += 4) {
        int sofs = __builtin_amdgcn_ds_bpermute(addrv, sc);
        int ewi  = __builtin_amdgcn_ds_bpermute(addrv, (int)__float_as_uint(e));
        addrv += 16;
        float ew = __uint_as_float((unsigned)ewi);
        uint2 u = *(const uint2*)(hbase + (unsigned)(sofs + colb));
        a0 = fmaf(__uint_as_float(u.x << 16), ew, a0);
        a1 = fmaf(__uint_as_float(u.x & 0xFFFF0000u), ew, a1);
        a2 = fmaf(__uint_as_float(u.y << 16), ew, a2);
        a3 = fmaf(__uint_as_float(u.y & 0xFFFF0000u), ew, a3);
      }
    }
    for (int base = r0c + 64; base < r1c; base += 64) {
      int cnt = min(64, r1c - base);
      int s128 = 0; float e2 = 0.f;
      if (lane < cnt) {
        s128 = csr[base + lane];
        float l = asb[s128 >> 7] + adc;
        l = fmaxf(l, 0.2f * l);
        e2 = __expf(l);
      }
      denl += e2;
      int cntUp = (cnt + 3) & ~3;
      int addrv = (lane >> 4) << 2;
      for (int j = 0; j < cntUp; j += 4) {
        int sofs = __builtin_amdgcn_ds_bpermute(addrv, s128);
        int ewi  = __builtin_amdgcn_ds_bpermute(addrv, (int)__float_as_uint(e2));
        addrv += 16;
        float ew = __uint_as_float((unsigned)ewi);
        uint2 u = *(const uint2*)(hbase + (unsigned)(sofs + colb));
        a0 = fmaf(__uint_as_float(u.x << 16), ew, a0);
        a1 = fmaf(__uint_as_float(u.x & 0xFFFF0000u), ew, a1);
        a2 = fmaf(__uint_as_float(u.y << 16), ew, a2);
        a3 = fmaf(__uint_as_float(u.y & 0xFFFF0000u), ew, a3);
      }
    }
    #pragma unroll
    for (int off = 16; off <= 32; off <<= 1) {
      a0 += __shfl_xor(a0, off, 64); a1 += __shfl_xor(a1, off, 64);
      a2 += __shfl_xor(a2, off, 64); a3 += __shfl_xor(a3, off, 64);
    }
    float den = denl;
    #pragma unroll
    for (int off = 32; off; off >>= 1) den += __shfl_xor(den, off, 64);
    float inv = 1.f / (den + 1e-16f);
    if (lane < 16) {
      float4 o;
      o.x = fmaf(a0, inv, bv4.x); o.y = fmaf(a1, inv, bv4.y);
      o.z = fmaf(a2, inv, bv4.z); o.w = fmaf(a3, inv, bv4.w);
      ((float4*)(out + (size_t)n * DHID))[L] = o;
    }
    r0c = r0n; r1c = r1n; adc = adn; sc = sn; avc = avn;
    r0n = r02; r1n = r12; adn = ad2;
    sn = 0;
    if (n2 < N && lane < min(64, r1n - r0n)) sn = csr[r0n + lane];
  }
}

extern "C" void kernel_launch(void* const* d_in, const int* in_sizes, int n_in,
                              void* d_out, int out_size, void* d_ws, size_t ws_size,
                              hipStream_t stream) {
  const float* x   = (const float*)d_in[0];
  const int*   ei  = (const int*)d_in[1];
  const float* W1  = (const float*)d_in[2];
  const float* as1 = (const float*)d_in[3];
  const float* ad1 = (const float*)d_in[4];
  const float* b1  = (const float*)d_in[5];
  const float* W2  = (const float*)d_in[6];
  const float* as2 = (const float*)d_in[7];
  const float* ad2 = (const float*)d_in[8];
  const float* b2  = (const float*)d_in[9];

  int N = in_sizes[0] / 128;
  int E = in_sizes[1] / 2;
  const int* srcp = ei;
  const int* dstp = ei + E;

  float* emb  = (float*)d_out;
  float* out2 = emb + (size_t)N * DHID;

  char* w = (char*)d_ws;
  auto alloc = [&](size_t bytes) { char* p = w; w += (bytes + 255) & ~(size_t)255; return p; };
  int NR = ((N + 63) / 64) * 64;
  int* roff = (int*)alloc((size_t)(N + 1) * 4);
  int* csr  = (int*)alloc((size_t)(E + N) * 4);
  int* bcnt = (int*)alloc(1024);
  char* scr0 = alloc((size_t)NR * 128 * 2);   // bkt, later hb2
  short* hb = (short*)alloc((size_t)NR * 64 * 2);
  float* asb = (float*)alloc((size_t)N * 4);
  float* adb = (float*)alloc((size_t)N * 4);
  float* asb2 = (float*)alloc((size_t)N * 4);
  float* adb2 = (float*)alloc((size_t)N * 4);
  short* hb2 = (short*)scr0;      // overlay: bkt dead before k_aggGemm writes hb2
  int* bkt  = (int*)scr0;

  int nsb = (N + SUBSZ - 1) >> SUBSH;          // sub-buckets (<=256 assumed)
  int cap = E / nsb + 4096;                    // per-sub-bucket capacity (ints)

  int NBLK = (N + 63) / 64;
  int nbkt = (E + EB - 1) / EB;

  hipMemsetAsync(bcnt, 0, (size_t)nsb * 4, stream);
  k_fusedA<<<nbkt + NBLK, 256, 0, stream>>>(srcp, dstp, bkt, bcnt, E, nsb, cap, nbkt,
                                            x, W1, as1, ad1, hb, asb, adb, N);
  k_place2<<<nsb, 256, 0, stream>>>(bkt, bcnt, roff, csr, N, nsb, cap);

  k_aggGemm<<<NBLK, 256, 0, stream>>>(roff, csr, asb, adb, hb, b1, emb,
                                      W2, as2, ad2, hb2, asb2, adb2, N);
  k_agg<<<2048, 256, 0, stream>>>(roff, csr, asb2, adb2, hb2, b2, out2, N);
}

// Round 16
// 155.969 us; speedup vs baseline: 1.2959x; 1.2959x over previous
//
#include <hip/hip_runtime.h>
#include <hip/hip_bf16.h>

#define DHID 64
#define SUBSH 9
#define SUBSZ (1 << SUBSH)     // 512 dst nodes per sub-bucket
#define PCAP 16384             // LDS staging cap (ints) in k_place2
#define EB 4096                // edges per block in bucket pass
typedef __attribute__((ext_vector_type(8))) short short8;
typedef __attribute__((ext_vector_type(4))) float f32x4;

static __device__ __forceinline__ short tobf(float f) {
  __hip_bfloat16 h = __float2bfloat16(f);
  return *reinterpret_cast<short*>(&h);
}

// ---------- fused A: edge bucket partition (blocks < nbkt) || layer-1 MFMA gemm ----------
__global__ __launch_bounds__(256)
void k_fusedA(const int* __restrict__ src, const int* __restrict__ dst,
              int* __restrict__ bkt, int* __restrict__ bcnt,
              int E, int nsb, int cap, int nbkt,
              const float* __restrict__ xf, const float* __restrict__ W1,
              const float* __restrict__ a_s, const float* __restrict__ a_d,
              short* __restrict__ hb, float* __restrict__ asb,
              float* __restrict__ adb, int N) {
  __shared__ int lcnt[256];
  __shared__ int lbase[256];
  __shared__ __align__(16) short ldsB[64 * 128];
  int tid = threadIdx.x;
  if (blockIdx.x < nbkt) {
    // ---- bucket path: single-pass local rank, payload (src<<9)|(d&511) ----
    int c0 = blockIdx.x * EB;
    for (int i = tid; i < nsb; i += 256) lcnt[i] = 0;
    __syncthreads();
    int wloc[16], uloc[16], rloc[16];
    #pragma unroll
    for (int k = 0; k < 16; k++) {
      int i = c0 + tid + k * 256;
      if (i < E) {
        int d = dst[i];
        int w = d >> SUBSH;
        wloc[k] = w;
        uloc[k] = (src[i] << SUBSH) | (d & (SUBSZ - 1));
        rloc[k] = atomicAdd(&lcnt[w], 1);
      } else wloc[k] = -1;
    }
    __syncthreads();
    for (int i = tid; i < nsb; i += 256) lbase[i] = atomicAdd(&bcnt[i], lcnt[i]);
    __syncthreads();
    #pragma unroll
    for (int k = 0; k < 16; k++) {
      int w = wloc[k];
      if (w >= 0) bkt[(size_t)w * cap + lbase[w] + rloc[k]] = uloc[k];
    }
    return;
  }
  // ---- mgemm1 path (K=128): A per-lane fp32->bf16; B = W1 self-converted ----
  int n0 = (blockIdx.x - nbkt) * 64;
  for (int e = tid; e < 128 * 64; e += 256) {
    int k = e >> 6, c = e & 63;
    ldsB[c * 128 + (k ^ ((c & 7) << 3))] = tobf(W1[e]);
  }
  __syncthreads();

  int l = tid & 63, w = tid >> 6;
  int c = l & 15, g = l >> 4;
  f32x4 acc[4];
  #pragma unroll
  for (int t = 0; t < 4; t++) acc[t] = (f32x4){0.f, 0.f, 0.f, 0.f};

  int arow = 16 * w + c;
  int row0 = n0 + arow;
  const float* xr = xf + (size_t)row0 * 128;
  bool okr = row0 < N;
  short8 afr[4];
  #pragma unroll
  for (int s = 0; s < 4; s++) {
    int ke = s * 32 + g * 8;
    float4 u0 = make_float4(0.f, 0.f, 0.f, 0.f), u1 = u0;
    if (okr) { u0 = *(const float4*)(xr + ke); u1 = *(const float4*)(xr + ke + 4); }
    short8 af;
    af[0] = tobf(u0.x); af[1] = tobf(u0.y); af[2] = tobf(u0.z); af[3] = tobf(u0.w);
    af[4] = tobf(u1.x); af[5] = tobf(u1.y); af[6] = tobf(u1.z); af[7] = tobf(u1.w);
    afr[s] = af;
  }
  #pragma unroll
  for (int s = 0; s < 4; s++) {
    int ke = s * 32 + g * 8;
    #pragma unroll
    for (int t = 0; t < 4; t++) {
      int bcol = 16 * t + c;
      short8 bf = *(const short8*)(ldsB + bcol * 128 + (ke ^ ((bcol & 7) << 3)));
      acc[t] = __builtin_amdgcn_mfma_f32_16x16x32_bf16(afr[s], bf, acc[t], 0, 0, 0);
    }
  }
  float av_s[4], av_d[4];
  #pragma unroll
  for (int t = 0; t < 4; t++) { av_s[t] = a_s[16 * t + c]; av_d[t] = a_d[16 * t + c]; }
  #pragma unroll
  for (int q = 0; q < 4; q++) {
    int row = n0 + 16 * w + g * 4 + q;
    bool ok = row < N;
    float rs = 0.f, rd = 0.f;
    #pragma unroll
    for (int t = 0; t < 4; t++) {
      float v = acc[t][q];
      if (ok) hb[(size_t)row * 64 + 16 * t + c] = tobf(v);
      rs += v * av_s[t]; rd += v * av_d[t];
    }
    #pragma unroll
    for (int off = 1; off < 16; off <<= 1) {
      rs += __shfl_xor(rs, off, 64);
      rd += __shfl_xor(rd, off, 64);
    }
    if (ok && c == 0) { asb[row] = rs; adb[row] = rd; }
  }
}

// ---------- merged count + scan + place (one block per sub-bucket) ----------
__global__ __launch_bounds__(256)
void k_place2(const int* __restrict__ bkt, const int* __restrict__ bcnt,
              int* __restrict__ roff, int* __restrict__ csr,
              int N, int nsb, int cap) {
  __shared__ int scanbuf[256];
  __shared__ int h[SUBSZ];
  __shared__ int roff_l[SUBSZ + 1];
  __shared__ int lcnt[SUBSZ];
  __shared__ int stage[PCAP];
  __shared__ int sbase;
  int sb = blockIdx.x, tid = threadIdx.x;
  int d0 = sb << SUBSH;
  int nn = min(N - d0, SUBSZ);

  int tot = 0;
  if (tid < nsb) tot = bcnt[tid] + min(N - (tid << SUBSH), SUBSZ);
  scanbuf[tid] = tot; __syncthreads();
  for (int off = 1; off < 256; off <<= 1) {
    int t = (tid >= off) ? scanbuf[tid - off] : 0;
    __syncthreads(); scanbuf[tid] += t; __syncthreads();
  }
  if (tid == sb) sbase = scanbuf[tid] - tot;
  __syncthreads();

  for (int j = tid; j < SUBSZ; j += 256) { h[j] = 1; lcnt[j] = 0; }
  __syncthreads();
  int nE = bcnt[sb];
  const int* b = bkt + (size_t)sb * cap;
  for (int i = tid; i < nE; i += 256) atomicAdd(&h[b[i] & (SUBSZ - 1)], 1);
  __syncthreads();

  int a0 = h[2 * tid], a1 = h[2 * tid + 1];
  int s = a0 + a1;
  scanbuf[tid] = s; __syncthreads();
  for (int off = 1; off < 256; off <<= 1) {
    int t = (tid >= off) ? scanbuf[tid - off] : 0;
    __syncthreads(); scanbuf[tid] += t; __syncthreads();
  }
  int excl = sbase + scanbuf[tid] - s;
  roff_l[2 * tid] = excl;
  roff_l[2 * tid + 1] = excl + a0;
  if (tid == 255) roff_l[SUBSZ] = sbase + scanbuf[255];
  __syncthreads();

  for (int j = tid; j < nn; j += 256) roff[d0 + j] = roff_l[j];
  if (d0 + nn == N && tid == 0) roff[N] = roff_l[nn];

  int base0 = roff_l[0];
  int span = roff_l[nn] - base0;
  if (span <= PCAP) {
    for (int d = tid; d < nn; d += 256) stage[roff_l[d] - base0] = (d0 + d) << 7; // self-loop
    for (int i = tid; i < nE; i += 256) {
      int u = b[i];
      int dl = u & (SUBSZ - 1);
      int rk = 1 + atomicAdd(&lcnt[dl], 1);
      stage[roff_l[dl] - base0 + rk] = (u >> SUBSH) << 7;
    }
    __syncthreads();
    for (int j = tid; j < span; j += 256) csr[base0 + j] = stage[j];
  } else {  // correctness fallback (never for random graphs)
    for (int d = tid; d < nn; d += 256) csr[roff_l[d]] = (d0 + d) << 7;
    for (int i = tid; i < nE; i += 256) {
      int u = b[i];
      int dl = u & (SUBSZ - 1);
      int rk = 1 + atomicAdd(&lcnt[dl], 1);
      csr[roff_l[dl] + rk] = (u >> SUBSH) << 7;
    }
  }
}

// ---------- layer-2 MFMA gemm: A per-lane from emb f32 (in-reg convert),
// B = W2 self-converted into LDS ----------
__global__ __launch_bounds__(256)
void k_mgemm2(const float* __restrict__ emb, const float* __restrict__ W2,
              const float* __restrict__ a_s, const float* __restrict__ a_d,
              short* __restrict__ hb, float* __restrict__ asb,
              float* __restrict__ adb, int N) {
  __shared__ __align__(16) short ldsB[64 * 64];
  int tid = threadIdx.x;
  int n0 = blockIdx.x * 64;
  for (int e = tid; e < 64 * 64; e += 256) {
    int k = e >> 6, c = e & 63;
    ldsB[c * 64 + (k ^ ((c & 7) << 3))] = tobf(W2[e]);
  }
  __syncthreads();

  int l = tid & 63, w = tid >> 6;
  int c = l & 15, g = l >> 4;
  f32x4 acc[4];
  #pragma unroll
  for (int t = 0; t < 4; t++) acc[t] = (f32x4){0.f, 0.f, 0.f, 0.f};
  int arow = 16 * w + c;
  int row0 = n0 + arow;
  const float* xr = emb + (size_t)row0 * 64;
  bool okr = row0 < N;
  short8 afr[2];
  #pragma unroll
  for (int s = 0; s < 2; s++) {
    int ke = s * 32 + g * 8;
    float4 u0 = make_float4(0.f, 0.f, 0.f, 0.f), u1 = u0;
    if (okr) { u0 = *(const float4*)(xr + ke); u1 = *(const float4*)(xr + ke + 4); }
    short8 af;
    af[0] = tobf(u0.x); af[1] = tobf(u0.y); af[2] = tobf(u0.z); af[3] = tobf(u0.w);
    af[4] = tobf(u1.x); af[5] = tobf(u1.y); af[6] = tobf(u1.z); af[7] = tobf(u1.w);
    afr[s] = af;
  }
  #pragma unroll
  for (int s = 0; s < 2; s++) {
    int ke = s * 32 + g * 8;
    #pragma unroll
    for (int t = 0; t < 4; t++) {
      int bcol = 16 * t + c;
      short8 bf = *(const short8*)(ldsB + bcol * 64 + (ke ^ ((bcol & 7) << 3)));
      acc[t] = __builtin_amdgcn_mfma_f32_16x16x32_bf16(afr[s], bf, acc[t], 0, 0, 0);
    }
  }
  float av_s[4], av_d[4];
  #pragma unroll
  for (int t = 0; t < 4; t++) { av_s[t] = a_s[16 * t + c]; av_d[t] = a_d[16 * t + c]; }
  #pragma unroll
  for (int q = 0; q < 4; q++) {
    int row = n0 + 16 * w + g * 4 + q;
    bool ok = row < N;
    float rs = 0.f, rd = 0.f;
    #pragma unroll
    for (int t = 0; t < 4; t++) {
      float v = acc[t][q];
      if (ok) hb[(size_t)row * 64 + 16 * t + c] = tobf(v);
      rs += v * av_s[t]; rd += v * av_d[t];
    }
    #pragma unroll
    for (int off = 1; off < 16; off <<= 1) {
      rs += __shfl_xor(rs, off, 64);
      rd += __shfl_xor(rd, off, 64);
    }
    if (ok && c == 0) { asb[row] = rs; adb[row] = rd; }
  }
}

// ---------- sparse: fused softmax + aggregation, 3-stage node pipeline ----------
__global__ void k_agg(const int* __restrict__ roff, const int* __restrict__ csr,
                      const float* __restrict__ asb, const float* __restrict__ adb,
                      const short* __restrict__ hb, const float* __restrict__ b,
                      float* __restrict__ out, int N, int relu) {
  const char* hbase = (const char*)hb;
  int lane = threadIdx.x & 63;
  int colb = (lane & 15) * 8;
  int L = lane & 15;
  int wid = blockIdx.x * (blockDim.x >> 6) + (threadIdx.x >> 6);
  int nw = gridDim.x * (blockDim.x >> 6);
  float4 bv4 = ((const float4*)b)[L];

  int r0c = 0, r1c = 0, sc = 0, r0n = 0, r1n = 0, sn = 0;
  float adc = 0.f, avc = 0.f, adn = 0.f;
  if (wid < N) {
    r0c = roff[wid]; r1c = roff[wid + 1]; adc = adb[wid];
    if (lane < min(64, r1c - r0c)) sc = csr[r0c + lane];
    avc = asb[sc >> 7];
  }
  if (wid + nw < N) {
    r0n = roff[wid + nw]; r1n = roff[wid + nw + 1]; adn = adb[wid + nw];
    if (lane < min(64, r1n - r0n)) sn = csr[r0n + lane];
  }

  for (int n = wid; n < N; n += nw) {
    int cnt0 = min(64, r1c - r0c);
    float e = 0.f;
    if (lane < cnt0) {
      float l = avc + adc;
      l = fmaxf(l, 0.2f * l);
      e = __expf(l);
    }
    int n2 = n + 2 * nw;
    int r02 = 0, r12 = 0; float ad2 = 0.f;
    if (n2 < N) { r02 = roff[n2]; r12 = roff[n2 + 1]; ad2 = adb[n2]; }
    float avn = asb[sn >> 7];

    float a0 = 0.f, a1 = 0.f, a2 = 0.f, a3 = 0.f, denl = e;
    {
      int cntUp = (cnt0 + 3) & ~3;
      int addrv = (lane >> 4) << 2;
      #pragma unroll 4
      for (int j = 0; j < cntUp; j += 4) {
        int sofs = __builtin_amdgcn_ds_bpermute(addrv, sc);
        int ewi  = __builtin_amdgcn_ds_bpermute(addrv, (int)__float_as_uint(e));
        addrv += 16;
        float ew = __uint_as_float((unsigned)ewi);
        uint2 u = *(const uint2*)(hbase + (unsigned)(sofs + colb));
        a0 = fmaf(__uint_as_float(u.x << 16), ew, a0);
        a1 = fmaf(__uint_as_float(u.x & 0xFFFF0000u), ew, a1);
        a2 = fmaf(__uint_as_float(u.y << 16), ew, a2);
        a3 = fmaf(__uint_as_float(u.y & 0xFFFF0000u), ew, a3);
      }
    }
    for (int base = r0c + 64; base < r1c; base += 64) {
      int cnt = min(64, r1c - base);
      int s128 = 0; float e2 = 0.f;
      if (lane < cnt) {
        s128 = csr[base + lane];
        float l = asb[s128 >> 7] + adc;
        l = fmaxf(l, 0.2f * l);
        e2 = __expf(l);
      }
      denl += e2;
      int cntUp = (cnt + 3) & ~3;
      int addrv = (lane >> 4) << 2;
      for (int j = 0; j < cntUp; j += 4) {
        int sofs = __builtin_amdgcn_ds_bpermute(addrv, s128);
        int ewi  = __builtin_amdgcn_ds_bpermute(addrv, (int)__float_as_uint(e2));
        addrv += 16;
        float ew = __uint_as_float((unsigned)ewi);
        uint2 u = *(const uint2*)(hbase + (unsigned)(sofs + colb));
        a0 = fmaf(__uint_as_float(u.x << 16), ew, a0);
        a1 = fmaf(__uint_as_float(u.x & 0xFFFF0000u), ew, a1);
        a2 = fmaf(__uint_as_float(u.y << 16), ew, a2);
        a3 = fmaf(__uint_as_float(u.y & 0xFFFF0000u), ew, a3);
      }
    }
    #pragma unroll
    for (int off = 16; off <= 32; off <<= 1) {
      a0 += __shfl_xor(a0, off, 64); a1 += __shfl_xor(a1, off, 64);
      a2 += __shfl_xor(a2, off, 64); a3 += __shfl_xor(a3, off, 64);
    }
    float den = denl;
    #pragma unroll
    for (int off = 32; off; off >>= 1) den += __shfl_xor(den, off, 64);
    float inv = 1.f / (den + 1e-16f);
    if (lane < 16) {
      float4 o;
      o.x = fmaf(a0, inv, bv4.x); o.y = fmaf(a1, inv, bv4.y);
      o.z = fmaf(a2, inv, bv4.z); o.w = fmaf(a3, inv, bv4.w);
      if (relu) {
        o.x = fmaxf(o.x, 0.f); o.y = fmaxf(o.y, 0.f);
        o.z = fmaxf(o.z, 0.f); o.w = fmaxf(o.w, 0.f);
      }
      ((float4*)(out + (size_t)n * DHID))[L] = o;
    }
    r0c = r0n; r1c = r1n; adc = adn; sc = sn; avc = avn;
    r0n = r02; r1n = r12; adn = ad2;
    sn = 0;
    if (n2 < N && lane < min(64, r1n - r0n)) sn = csr[r0n + lane];
  }
}

extern "C" void kernel_launch(void* const* d_in, const int* in_sizes, int n_in,
                              void* d_out, int out_size, void* d_ws, size_t ws_size,
                              hipStream_t stream) {
  const float* x   = (const float*)d_in[0];
  const int*   ei  = (const int*)d_in[1];
  const float* W1  = (const float*)d_in[2];
  const float* as1 = (const float*)d_in[3];
  const float* ad1 = (const float*)d_in[4];
  const float* b1  = (const float*)d_in[5];
  const float* W2  = (const float*)d_in[6];
  const float* as2 = (const float*)d_in[7];
  const float* ad2 = (const float*)d_in[8];
  const float* b2  = (const float*)d_in[9];

  int N = in_sizes[0] / 128;
  int E = in_sizes[1] / 2;
  const int* srcp = ei;
  const int* dstp = ei + E;

  float* emb  = (float*)d_out;
  float* out2 = emb + (size_t)N * DHID;

  char* w = (char*)d_ws;
  auto alloc = [&](size_t bytes) { char* p = w; w += (bytes + 255) & ~(size_t)255; return p; };
  int NR = ((N + 63) / 64) * 64;
  int* roff = (int*)alloc((size_t)(N + 1) * 4);
  int* csr  = (int*)alloc((size_t)(E + N) * 4);
  int* bcnt = (int*)alloc(1024);
  char* scr0 = alloc((size_t)NR * 128 * 2);   // bkt, later hb2
  short* hb = (short*)alloc((size_t)NR * 64 * 2);
  float* asb = (float*)alloc((size_t)N * 4);
  float* adb = (float*)alloc((size_t)N * 4);
  float* asb2 = (float*)alloc((size_t)N * 4);
  float* adb2 = (float*)alloc((size_t)N * 4);
  short* hb2 = (short*)scr0;      // overlay: bkt dead after k_place2
  int* bkt  = (int*)scr0;

  int nsb = (N + SUBSZ - 1) >> SUBSH;          // sub-buckets (<=256 assumed)
  int cap = E / nsb + 4096;                    // per-sub-bucket capacity (ints)

  int NBLK = (N + 63) / 64;
  int nbkt = (E + EB - 1) / EB;

  hipMemsetAsync(bcnt, 0, (size_t)nsb * 4, stream);
  k_fusedA<<<nbkt + NBLK, 256, 0, stream>>>(srcp, dstp, bkt, bcnt, E, nsb, cap, nbkt,
                                            x, W1, as1, ad1, hb, asb, adb, N);
  k_place2<<<nsb, 256, 0, stream>>>(bkt, bcnt, roff, csr, N, nsb, cap);

  k_agg<<<2048, 256, 0, stream>>>(roff, csr, asb, adb, hb, b1, emb, N, 1);
  k_mgemm2<<<NBLK, 256, 0, stream>>>(emb, W2, as2, ad2, hb2, asb2, adb2, N);
  k_agg<<<2048, 256, 0, stream>>>(roff, csr, asb2, adb2, hb2, b2, out2, N, 0);
}

// Round 17
// 153.834 us; speedup vs baseline: 1.3139x; 1.0139x over previous
//
#include <hip/hip_runtime.h>
#include <hip/hip_bf16.h>

#define DHID 64
#define SUBSH 8
#define SUBSZ (1 << SUBSH)     // 256 dst nodes per sub-bucket
#define PCAP 8192              // LDS staging cap (ints) in k_place2
#define EB 4096                // edges per block in bucket pass
typedef __attribute__((ext_vector_type(8))) short short8;
typedef __attribute__((ext_vector_type(4))) float f32x4;

static __device__ __forceinline__ short tobf(float f) {
  __hip_bfloat16 h = __float2bfloat16(f);
  return *reinterpret_cast<short*>(&h);
}

// ---------- fused A: edge bucket partition (blocks < nbkt) || layer-1 MFMA gemm ----------
__global__ __launch_bounds__(256)
void k_fusedA(const int* __restrict__ src, const int* __restrict__ dst,
              int* __restrict__ bkt, int* __restrict__ bcnt,
              int E, int nsb, int cap, int nbkt,
              const float* __restrict__ xf, const float* __restrict__ W1,
              const float* __restrict__ a_s, const float* __restrict__ a_d,
              short* __restrict__ hb, float* __restrict__ asb,
              float* __restrict__ adb, int N) {
  __shared__ int lcnt[512];
  __shared__ int lbase[512];
  __shared__ __align__(16) short ldsB[64 * 128];
  int tid = threadIdx.x;
  if (blockIdx.x < nbkt) {
    // ---- bucket path: single-pass local rank, payload (src<<8)|(d&255) ----
    int c0 = blockIdx.x * EB;
    for (int i = tid; i < nsb; i += 256) lcnt[i] = 0;
    __syncthreads();
    int wloc[16], uloc[16], rloc[16];
    #pragma unroll
    for (int k = 0; k < 16; k++) {
      int i = c0 + tid + k * 256;
      if (i < E) {
        int d = dst[i];
        int w = d >> SUBSH;
        wloc[k] = w;
        uloc[k] = (src[i] << SUBSH) | (d & (SUBSZ - 1));
        rloc[k] = atomicAdd(&lcnt[w], 1);
      } else wloc[k] = -1;
    }
    __syncthreads();
    for (int i = tid; i < nsb; i += 256) lbase[i] = atomicAdd(&bcnt[i], lcnt[i]);
    __syncthreads();
    #pragma unroll
    for (int k = 0; k < 16; k++) {
      int w = wloc[k];
      if (w >= 0) bkt[(size_t)w * cap + lbase[w] + rloc[k]] = uloc[k];
    }
    return;
  }
  // ---- mgemm1 path (K=128): A per-lane fp32->bf16; B = W1 self-converted ----
  int n0 = (blockIdx.x - nbkt) * 64;
  for (int e = tid; e < 128 * 64; e += 256) {
    int k = e >> 6, c = e & 63;
    ldsB[c * 128 + (k ^ ((c & 7) << 3))] = tobf(W1[e]);
  }
  __syncthreads();

  int l = tid & 63, w = tid >> 6;
  int c = l & 15, g = l >> 4;
  f32x4 acc[4];
  #pragma unroll
  for (int t = 0; t < 4; t++) acc[t] = (f32x4){0.f, 0.f, 0.f, 0.f};

  int arow = 16 * w + c;
  int row0 = n0 + arow;
  const float* xr = xf + (size_t)row0 * 128;
  bool okr = row0 < N;
  short8 afr[4];
  #pragma unroll
  for (int s = 0; s < 4; s++) {
    int ke = s * 32 + g * 8;
    float4 u0 = make_float4(0.f, 0.f, 0.f, 0.f), u1 = u0;
    if (okr) { u0 = *(const float4*)(xr + ke); u1 = *(const float4*)(xr + ke + 4); }
    short8 af;
    af[0] = tobf(u0.x); af[1] = tobf(u0.y); af[2] = tobf(u0.z); af[3] = tobf(u0.w);
    af[4] = tobf(u1.x); af[5] = tobf(u1.y); af[6] = tobf(u1.z); af[7] = tobf(u1.w);
    afr[s] = af;
  }
  #pragma unroll
  for (int s = 0; s < 4; s++) {
    int ke = s * 32 + g * 8;
    #pragma unroll
    for (int t = 0; t < 4; t++) {
      int bcol = 16 * t + c;
      short8 bf = *(const short8*)(ldsB + bcol * 128 + (ke ^ ((bcol & 7) << 3)));
      acc[t] = __builtin_amdgcn_mfma_f32_16x16x32_bf16(afr[s], bf, acc[t], 0, 0, 0);
    }
  }
  float av_s[4], av_d[4];
  #pragma unroll
  for (int t = 0; t < 4; t++) { av_s[t] = a_s[16 * t + c]; av_d[t] = a_d[16 * t + c]; }
  #pragma unroll
  for (int q = 0; q < 4; q++) {
    int row = n0 + 16 * w + g * 4 + q;
    bool ok = row < N;
    float rs = 0.f, rd = 0.f;
    #pragma unroll
    for (int t = 0; t < 4; t++) {
      float v = acc[t][q];
      if (ok) hb[(size_t)row * 64 + 16 * t + c] = tobf(v);
      rs += v * av_s[t]; rd += v * av_d[t];
    }
    #pragma unroll
    for (int off = 1; off < 16; off <<= 1) {
      rs += __shfl_xor(rs, off, 64);
      rd += __shfl_xor(rd, off, 64);
    }
    if (ok && c == 0) { asb[row] = rs; adb[row] = rd; }
  }
}

// ---------- merged count + scan + place (one block per sub-bucket, nsb<=512) ----------
__global__ __launch_bounds__(256)
void k_place2(const int* __restrict__ bkt, const int* __restrict__ bcnt,
              int* __restrict__ roff, int* __restrict__ csr,
              int N, int nsb, int cap) {
  __shared__ int scanbuf[256];
  __shared__ int h[SUBSZ];
  __shared__ int roff_l[SUBSZ + 1];
  __shared__ int lcnt[SUBSZ];
  __shared__ int stage[PCAP];
  __shared__ int sbase;
  int sb = blockIdx.x, tid = threadIdx.x;
  int d0 = sb << SUBSH;
  int nn = min(N - d0, SUBSZ);

  // global base: pair-scan over nsb (<=512) totals
  int k0 = 2 * tid, k1 = 2 * tid + 1;
  int t0 = 0, t1 = 0;
  if (k0 < nsb) t0 = bcnt[k0] + min(N - (k0 << SUBSH), SUBSZ);
  if (k1 < nsb) t1 = bcnt[k1] + min(N - (k1 << SUBSH), SUBSZ);
  int psum = t0 + t1;
  scanbuf[tid] = psum; __syncthreads();
  for (int off = 1; off < 256; off <<= 1) {
    int t = (tid >= off) ? scanbuf[tid - off] : 0;
    __syncthreads(); scanbuf[tid] += t; __syncthreads();
  }
  if (tid == (sb >> 1)) {
    int excl_pair = scanbuf[tid] - psum;
    sbase = (sb & 1) ? (excl_pair + t0) : excl_pair;
  }
  __syncthreads();

  // per-dst histogram (init 1: self-loop)
  for (int j = tid; j < SUBSZ; j += 256) { h[j] = 1; lcnt[j] = 0; }
  __syncthreads();
  int nE = bcnt[sb];
  const int* b = bkt + (size_t)sb * cap;
  for (int i = tid; i < nE; i += 256) atomicAdd(&h[b[i] & (SUBSZ - 1)], 1);
  __syncthreads();

  // 256-wide exclusive scan
  int a = h[tid];
  scanbuf[tid] = a; __syncthreads();
  for (int off = 1; off < 256; off <<= 1) {
    int t = (tid >= off) ? scanbuf[tid - off] : 0;
    __syncthreads(); scanbuf[tid] += t; __syncthreads();
  }
  roff_l[tid] = sbase + scanbuf[tid] - a;
  if (tid == 255) roff_l[SUBSZ] = sbase + scanbuf[255];
  __syncthreads();

  for (int j = tid; j < nn; j += 256) roff[d0 + j] = roff_l[j];
  if (d0 + nn == N && tid == 0) roff[N] = roff_l[nn];

  int base0 = roff_l[0];
  int span = roff_l[nn] - base0;
  if (span <= PCAP) {
    for (int d = tid; d < nn; d += 256) stage[roff_l[d] - base0] = (d0 + d) << 7; // self-loop
    for (int i = tid; i < nE; i += 256) {
      int u = b[i];
      int dl = u & (SUBSZ - 1);
      int rk = 1 + atomicAdd(&lcnt[dl], 1);
      stage[roff_l[dl] - base0 + rk] = (u >> SUBSH) << 7;
    }
    __syncthreads();
    for (int j = tid; j < span; j += 256) csr[base0 + j] = stage[j];
  } else {  // correctness fallback (never for random graphs)
    for (int d = tid; d < nn; d += 256) csr[roff_l[d]] = (d0 + d) << 7;
    for (int i = tid; i < nE; i += 256) {
      int u = b[i];
      int dl = u & (SUBSZ - 1);
      int rk = 1 + atomicAdd(&lcnt[dl], 1);
      csr[roff_l[dl] + rk] = (u >> SUBSH) << 7;
    }
  }
}

// ---------- layer-2 MFMA gemm: A per-lane from emb f32 (in-reg convert),
// B = W2 self-converted into LDS ----------
__global__ __launch_bounds__(256)
void k_mgemm2(const float* __restrict__ emb, const float* __restrict__ W2,
              const float* __restrict__ a_s, const float* __restrict__ a_d,
              short* __restrict__ hb, float* __restrict__ asb,
              float* __restrict__ adb, int N) {
  __shared__ __align__(16) short ldsB[64 * 64];
  int tid = threadIdx.x;
  int n0 = blockIdx.x * 64;
  for (int e = tid; e < 64 * 64; e += 256) {
    int k = e >> 6, c = e & 63;
    ldsB[c * 64 + (k ^ ((c & 7) << 3))] = tobf(W2[e]);
  }
  __syncthreads();

  int l = tid & 63, w = tid >> 6;
  int c = l & 15, g = l >> 4;
  f32x4 acc[4];
  #pragma unroll
  for (int t = 0; t < 4; t++) acc[t] = (f32x4){0.f, 0.f, 0.f, 0.f};
  int arow = 16 * w + c;
  int row0 = n0 + arow;
  const float* xr = emb + (size_t)row0 * 64;
  bool okr = row0 < N;
  short8 afr[2];
  #pragma unroll
  for (int s = 0; s < 2; s++) {
    int ke = s * 32 + g * 8;
    float4 u0 = make_float4(0.f, 0.f, 0.f, 0.f), u1 = u0;
    if (okr) { u0 = *(const float4*)(xr + ke); u1 = *(const float4*)(xr + ke + 4); }
    short8 af;
    af[0] = tobf(u0.x); af[1] = tobf(u0.y); af[2] = tobf(u0.z); af[3] = tobf(u0.w);
    af[4] = tobf(u1.x); af[5] = tobf(u1.y); af[6] = tobf(u1.z); af[7] = tobf(u1.w);
    afr[s] = af;
  }
  #pragma unroll
  for (int s = 0; s < 2; s++) {
    int ke = s * 32 + g * 8;
    #pragma unroll
    for (int t = 0; t < 4; t++) {
      int bcol = 16 * t + c;
      short8 bf = *(const short8*)(ldsB + bcol * 64 + (ke ^ ((bcol & 7) << 3)));
      acc[t] = __builtin_amdgcn_mfma_f32_16x16x32_bf16(afr[s], bf, acc[t], 0, 0, 0);
    }
  }
  float av_s[4], av_d[4];
  #pragma unroll
  for (int t = 0; t < 4; t++) { av_s[t] = a_s[16 * t + c]; av_d[t] = a_d[16 * t + c]; }
  #pragma unroll
  for (int q = 0; q < 4; q++) {
    int row = n0 + 16 * w + g * 4 + q;
    bool ok = row < N;
    float rs = 0.f, rd = 0.f;
    #pragma unroll
    for (int t = 0; t < 4; t++) {
      float v = acc[t][q];
      if (ok) hb[(size_t)row * 64 + 16 * t + c] = tobf(v);
      rs += v * av_s[t]; rd += v * av_d[t];
    }
    #pragma unroll
    for (int off = 1; off < 16; off <<= 1) {
      rs += __shfl_xor(rs, off, 64);
      rd += __shfl_xor(rd, off, 64);
    }
    if (ok && c == 0) { asb[row] = rs; adb[row] = rd; }
  }
}

// ---------- sparse: fused softmax + aggregation, 3-stage node pipeline ----------
__global__ void k_agg(const int* __restrict__ roff, const int* __restrict__ csr,
                      const float* __restrict__ asb, const float* __restrict__ adb,
                      const short* __restrict__ hb, const float* __restrict__ b,
                      float* __restrict__ out, int N, int relu) {
  const char* hbase = (const char*)hb;
  int lane = threadIdx.x & 63;
  int colb = (lane & 15) * 8;
  int L = lane & 15;
  int wid = blockIdx.x * (blockDim.x >> 6) + (threadIdx.x >> 6);
  int nw = gridDim.x * (blockDim.x >> 6);
  float4 bv4 = ((const float4*)b)[L];

  int r0c = 0, r1c = 0, sc = 0, r0n = 0, r1n = 0, sn = 0;
  float adc = 0.f, avc = 0.f, adn = 0.f;
  if (wid < N) {
    r0c = roff[wid]; r1c = roff[wid + 1]; adc = adb[wid];
    if (lane < min(64, r1c - r0c)) sc = csr[r0c + lane];
    avc = asb[sc >> 7];
  }
  if (wid + nw < N) {
    r0n = roff[wid + nw]; r1n = roff[wid + nw + 1]; adn = adb[wid + nw];
    if (lane < min(64, r1n - r0n)) sn = csr[r0n + lane];
  }

  for (int n = wid; n < N; n += nw) {
    int cnt0 = min(64, r1c - r0c);
    float e = 0.f;
    if (lane < cnt0) {
      float l = avc + adc;
      l = fmaxf(l, 0.2f * l);
      e = __expf(l);
    }
    int n2 = n + 2 * nw;
    int r02 = 0, r12 = 0; float ad2 = 0.f;
    if (n2 < N) { r02 = roff[n2]; r12 = roff[n2 + 1]; ad2 = adb[n2]; }
    float avn = asb[sn >> 7];

    float a0 = 0.f, a1 = 0.f, a2 = 0.f, a3 = 0.f, denl = e;
    {
      int cntUp = (cnt0 + 3) & ~3;
      int addrv = (lane >> 4) << 2;
      #pragma unroll 4
      for (int j = 0; j < cntUp; j += 4) {
        int sofs = __builtin_amdgcn_ds_bpermute(addrv, sc);
        int ewi  = __builtin_amdgcn_ds_bpermute(addrv, (int)__float_as_uint(e));
        addrv += 16;
        float ew = __uint_as_float((unsigned)ewi);
        uint2 u = *(const uint2*)(hbase + (unsigned)(sofs + colb));
        a0 = fmaf(__uint_as_float(u.x << 16), ew, a0);
        a1 = fmaf(__uint_as_float(u.x & 0xFFFF0000u), ew, a1);
        a2 = fmaf(__uint_as_float(u.y << 16), ew, a2);
        a3 = fmaf(__uint_as_float(u.y & 0xFFFF0000u), ew, a3);
      }
    }
    for (int base = r0c + 64; base < r1c; base += 64) {
      int cnt = min(64, r1c - base);
      int s128 = 0; float e2 = 0.f;
      if (lane < cnt) {
        s128 = csr[base + lane];
        float l = asb[s128 >> 7] + adc;
        l = fmaxf(l, 0.2f * l);
        e2 = __expf(l);
      }
      denl += e2;
      int cntUp = (cnt + 3) & ~3;
      int addrv = (lane >> 4) << 2;
      for (int j = 0; j < cntUp; j += 4) {
        int sofs = __builtin_amdgcn_ds_bpermute(addrv, s128);
        int ewi  = __builtin_amdgcn_ds_bpermute(addrv, (int)__float_as_uint(e2));
        addrv += 16;
        float ew = __uint_as_float((unsigned)ewi);
        uint2 u = *(const uint2*)(hbase + (unsigned)(sofs + colb));
        a0 = fmaf(__uint_as_float(u.x << 16), ew, a0);
        a1 = fmaf(__uint_as_float(u.x & 0xFFFF0000u), ew, a1);
        a2 = fmaf(__uint_as_float(u.y << 16), ew, a2);
        a3 = fmaf(__uint_as_float(u.y & 0xFFFF0000u), ew, a3);
      }
    }
    #pragma unroll
    for (int off = 16; off <= 32; off <<= 1) {
      a0 += __shfl_xor(a0, off, 64); a1 += __shfl_xor(a1, off, 64);
      a2 += __shfl_xor(a2, off, 64); a3 += __shfl_xor(a3, off, 64);
    }
    float den = denl;
    #pragma unroll
    for (int off = 32; off; off >>= 1) den += __shfl_xor(den, off, 64);
    float inv = 1.f / (den + 1e-16f);
    if (lane < 16) {
      float4 o;
      o.x = fmaf(a0, inv, bv4.x); o.y = fmaf(a1, inv, bv4.y);
      o.z = fmaf(a2, inv, bv4.z); o.w = fmaf(a3, inv, bv4.w);
      if (relu) {
        o.x = fmaxf(o.x, 0.f); o.y = fmaxf(o.y, 0.f);
        o.z = fmaxf(o.z, 0.f); o.w = fmaxf(o.w, 0.f);
      }
      ((float4*)(out + (size_t)n * DHID))[L] = o;
    }
    r0c = r0n; r1c = r1n; adc = adn; sc = sn; avc = avn;
    r0n = r02; r1n = r12; adn = ad2;
    sn = 0;
    if (n2 < N && lane < min(64, r1n - r0n)) sn = csr[r0n + lane];
  }
}

extern "C" void kernel_launch(void* const* d_in, const int* in_sizes, int n_in,
                              void* d_out, int out_size, void* d_ws, size_t ws_size,
                              hipStream_t stream) {
  const float* x   = (const float*)d_in[0];
  const int*   ei  = (const int*)d_in[1];
  const float* W1  = (const float*)d_in[2];
  const float* as1 = (const float*)d_in[3];
  const float* ad1 = (const float*)d_in[4];
  const float* b1  = (const float*)d_in[5];
  const float* W2  = (const float*)d_in[6];
  const float* as2 = (const float*)d_in[7];
  const float* ad2 = (const float*)d_in[8];
  const float* b2  = (const float*)d_in[9];

  int N = in_sizes[0] / 128;
  int E = in_sizes[1] / 2;
  const int* srcp = ei;
  const int* dstp = ei + E;

  float* emb  = (float*)d_out;
  float* out2 = emb + (size_t)N * DHID;

  char* w = (char*)d_ws;
  auto alloc = [&](size_t bytes) { char* p = w; w += (bytes + 255) & ~(size_t)255; return p; };
  int NR = ((N + 63) / 64) * 64;
  int* roff = (int*)alloc((size_t)(N + 1) * 4);
  int* csr  = (int*)alloc((size_t)(E + N) * 4);
  int* bcnt = (int*)alloc(2048);
  char* scr0 = alloc((size_t)NR * 128 * 2);   // bkt, later hb2
  short* hb = (short*)alloc((size_t)NR * 64 * 2);
  float* asb = (float*)alloc((size_t)N * 4);
  float* adb = (float*)alloc((size_t)N * 4);
  float* asb2 = (float*)alloc((size_t)N * 4);
  float* adb2 = (float*)alloc((size_t)N * 4);
  short* hb2 = (short*)scr0;      // overlay: bkt dead after k_place2
  int* bkt  = (int*)scr0;

  int nsb = (N + SUBSZ - 1) >> SUBSH;          // sub-buckets (<=512)
  int cap = E / nsb + 4096;                    // per-sub-bucket capacity (ints)

  int NBLK = (N + 63) / 64;
  int nbkt = (E + EB - 1) / EB;

  hipMemsetAsync(bcnt, 0, (size_t)nsb * 4, stream);
  k_fusedA<<<nbkt + NBLK, 256, 0, stream>>>(srcp, dstp, bkt, bcnt, E, nsb, cap, nbkt,
                                            x, W1, as1, ad1, hb, asb, adb, N);
  k_place2<<<nsb, 256, 0, stream>>>(bkt, bcnt, roff, csr, N, nsb, cap);

  k_agg<<<2048, 256, 0, stream>>>(roff, csr, asb, adb, hb, b1, emb, N, 1);
  k_mgemm2<<<NBLK, 256, 0, stream>>>(emb, W2, as2, ad2, hb2, asb2, adb2, N);
  k_agg<<<2048, 256, 0, stream>>>(roff, csr, asb2, adb2, hb2, b2, out2, N, 0);
}